// Round 1
// 782.804 us; speedup vs baseline: 1.1951x; 1.1951x over previous
//
#include <hip/hip_runtime.h>
#include <hip/hip_bf16.h>

typedef unsigned int u32;
typedef unsigned short u16;
typedef unsigned char u8;
typedef __attribute__((ext_vector_type(8))) __bf16 bfrag;   // 8 bf16 = 4 VGPRs (MFMA A/B operand)
typedef __attribute__((ext_vector_type(4))) float f32x4;    // MFMA C/D
typedef __attribute__((ext_vector_type(2))) float f32x2;

#define T_STEPS 4
#define N_NODES 50000
#define E_EDGES 1600000
#define HID 128
#define OUT_CH 16

#define NB 128                   // hist blocks; chunk = E/NB
#define CHUNK (E_EDGES / NB)     // 12500
#define NPAIR (N_NODES / 2)      // 25000 packed u16-pair histogram entries
#define SCAN4 13                 // int4s per thread in scan (1024*13=13312 >= 12500)

// ---- workspace layout (bytes); every per-t array has a 256-aligned stride ----
// All 4 timesteps' pipelines are independent (only GRU is recurrent), so each
// array is x4 and kernels batch over t via blockIdx.y.
#define H_STRIDE    6400000u     // h fp8 [N*128] u8
#define DEG_STRIDE  212992u      // deg [13312 int4 padded]
#define RS_STRIDE   212992u      // row_start [13312 int4]
#define ZP_STRIDE   16384u       // z_sum padded [128*32] f32
#define CSR_STRIDE  3200000u     // csr src [E] u16
#define RK_STRIDE   3200000u     // ranks [E] u16
#define HIST_STRIDE 12800000u    // hist [NB][NPAIR] u32

#define OFF_H     0u                                   // +4*H_STRIDE    = 25,600,000
#define OFF_DEG   25600000u                            // +4*DEG_STRIDE  = 26,451,968
#define OFF_RS    26451968u                            // +4*RS_STRIDE   = 27,303,936
#define OFF_ZPAD  27303936u                            // +4*ZP_STRIDE   = 27,369,472
#define OFF_CSR   27369472u                            // +4*CSR_STRIDE  = 40,169,472
#define OFF_WB    40169984u                            // W_gcn bf16     = 40,202,752
#define OFF_RANKS 40202752u                            // +4*RK_STRIDE   = 53,002,752
#define OFF_HIST  53002752u                            // +4*HIST_STRIDE ~ 104.2 MB (ws >= 409 MB)

__device__ __forceinline__ u8 f32_to_fp8(float v) {
    return (u8)(__builtin_amdgcn_cvt_pk_fp8_f32(v, v, 0, 0) & 0xFF);
}

// one-shot: W fp32 -> bf16 (32 KB, L1-resident for the GEMM)
__global__ void wbf_kernel(const float* __restrict__ W, __bf16* __restrict__ wb) {
    const int i = blockIdx.x * 256 + threadIdx.x;   // 16384
    wb[i] = (__bf16)W[i];
}

// h = fp8(x @ W^T + b) via MFMA 16x16x32 bf16, batched over t (blockIdx.y).
// Frag layouts (m89/m120-verified): A[m=lane&15][k=(lane>>4)*8+j],
// B[n=lane&15][k=(lane>>4)*8+j], C/D row=(lane>>4)*4+reg, col=lane&15.
__global__ __launch_bounds__(256) void gemm_mfma_kernel(const float* __restrict__ xs,
                                                        const __bf16* __restrict__ wb,
                                                        const float* __restrict__ b,
                                                        u8* __restrict__ h8_all) {
    const int lane = threadIdx.x & 63;
    const int wv   = threadIdx.x >> 6;      // 0..3 -> n-slice
    const int r16  = lane & 15;
    const int quad = lane >> 4;
    const int mb   = blockIdx.x;            // rows [16mb, 16mb+16)
    const int t    = blockIdx.y;
    const float* x = xs + (size_t)t * N_NODES * 128;
    u8* h8         = h8_all + (size_t)t * H_STRIDE;

    bfrag Bf[2][4];
#pragma unroll
    for (int nt = 0; nt < 2; ++nt) {
        const int c = wv * 32 + nt * 16 + r16;
#pragma unroll
        for (int ks = 0; ks < 4; ++ks)
            Bf[nt][ks] = *(const bfrag*)(wb + c * 128 + ks * 32 + quad * 8);
    }

    const float* xp = x + (size_t)(mb * 16 + r16) * 128 + quad * 8;
    bfrag Af[4];
#pragma unroll
    for (int ks = 0; ks < 4; ++ks) {
        const float* ap = xp + ks * 32;
#pragma unroll
        for (int j = 0; j < 8; ++j) Af[ks][j] = (__bf16)ap[j];
    }

    f32x4 acc0 = {0.f, 0.f, 0.f, 0.f};
    f32x4 acc1 = {0.f, 0.f, 0.f, 0.f};
#pragma unroll
    for (int ks = 0; ks < 4; ++ks) {
        acc0 = __builtin_amdgcn_mfma_f32_16x16x32_bf16(Af[ks], Bf[0][ks], acc0, 0, 0, 0);
        acc1 = __builtin_amdgcn_mfma_f32_16x16x32_bf16(Af[ks], Bf[1][ks], acc1, 0, 0, 0);
    }

    const int c0 = wv * 32 + r16;
    const float b0 = b[c0], b1 = b[c0 + 16];
#pragma unroll
    for (int r = 0; r < 4; ++r) {
        const size_t row = (size_t)(mb * 16 + quad * 4 + r) * 128;
        h8[row + c0]      = f32_to_fp8(acc0[r] + b0);
        h8[row + c0 + 16] = f32_to_fp8(acc1[r] + b1);
    }
}

// Block (b,t): LDS histogram of its 12500-edge chunk (u16 counts packed 2/u32),
// LDS-atomic return = local rank. No global atomics (R3 lesson: 1.6M
// device-scope atomics = 103 MB EA round-trips).
__global__ __launch_bounds__(512) void hist_rank_kernel(const int* __restrict__ edges,
                                                        u32* __restrict__ hist_all,
                                                        u16* __restrict__ ranks_all) {
    __shared__ u32 hloc[NPAIR / 2];          // 12500 u32 = 50 KB
    const int b = blockIdx.x;
    const int t = blockIdx.y;
    const int* dst = edges + (size_t)t * 2 * E_EDGES + E_EDGES;
    u16* ranks = ranks_all + (size_t)t * (RK_STRIDE / 2);
    const int base = b * CHUNK;
    u32* row = hist_all + (size_t)t * (HIST_STRIDE / 4) + (size_t)b * NPAIR;

#pragma unroll
    for (int half = 0; half < 2; ++half) {
        for (int j = threadIdx.x; j < NPAIR / 2; j += 512) hloc[j] = 0;
        __syncthreads();
        const int jlo = half * (NPAIR / 2);
        for (int i = threadIdx.x; i < CHUNK; i += 512) {
            const int d = dst[base + i];
            const int j = d >> 1;
            if ((j >= jlo) && (j < jlo + NPAIR / 2)) {
                const u32 inc = (d & 1) ? 0x10000u : 1u;
                const u32 old = atomicAdd(&hloc[j - jlo], inc);
                ranks[base + i] = (u16)((old >> ((d & 1) * 16)) & 0xFFFFu);
            }
        }
        __syncthreads();
        for (int j = threadIdx.x; j < NPAIR / 2; j += 512) row[jlo + j] = hloc[j];
        __syncthreads();
    }
}

// In-place exclusive scan over the NB block-rows for each node pair; emits deg.
__global__ void colscan_kernel(u32* __restrict__ hist_all, int* __restrict__ deg_all) {
    const int j = blockIdx.x * blockDim.x + threadIdx.x;
    if (j >= NPAIR) return;
    const int t = blockIdx.y;
    u32 lo = 0, hi = 0;
    u32* p = hist_all + (size_t)t * (HIST_STRIDE / 4) + j;
    int* deg = deg_all + (size_t)t * (DEG_STRIDE / 4);
#pragma unroll 8
    for (int b = 0; b < NB; ++b) {
        const u32 v = p[(size_t)b * NPAIR];
        p[(size_t)b * NPAIR] = lo | (hi << 16);
        lo += v & 0xFFFFu;
        hi += v >> 16;
    }
    deg[2 * j]     = (int)lo;
    deg[2 * j + 1] = (int)hi;
}

// One block per t. Fully unrolled + vectorized (R5 lesson: dynamic-trip
// scalar loops serialize ~100 round-trips). 13 int4/thread, all loads in
// flight before one waitcnt; deg tail pre-zeroed so row_start[50000]=E.
__global__ __launch_bounds__(1024) void scan_kernel(const int4* __restrict__ deg4_all,
                                                    int4* __restrict__ rs4_all) {
    __shared__ int part[1024];
    const int tid = threadIdx.x;
    const int t = blockIdx.y;
    const int4* deg4 = deg4_all + (size_t)t * (DEG_STRIDE / 16);
    int4* rs4 = rs4_all + (size_t)t * (RS_STRIDE / 16);
    int4 v[SCAN4];
#pragma unroll
    for (int j = 0; j < SCAN4; ++j) v[j] = deg4[tid * SCAN4 + j];
    int s = 0;
#pragma unroll
    for (int j = 0; j < SCAN4; ++j) s += v[j].x + v[j].y + v[j].z + v[j].w;
    part[tid] = s;
    __syncthreads();
    for (int d = 1; d < 1024; d <<= 1) {
        const int tmp = (tid >= d) ? part[tid - d] : 0;
        __syncthreads();
        part[tid] += tmp;
        __syncthreads();
    }
    int run = (tid == 0) ? 0 : part[tid - 1];
#pragma unroll
    for (int j = 0; j < SCAN4; ++j) {
        int4 o;
        o.x = run; run += v[j].x;
        o.y = run; run += v[j].y;
        o.z = run; run += v[j].z;
        o.w = run; run += v[j].w;
        rs4[tid * SCAN4 + j] = o;
    }
}

// pos = row_start[d] + colscan[b][d] + local_rank  -- atomic-free CSR fill.
__global__ __launch_bounds__(256) void fill_kernel(const int* __restrict__ edges,
                                                   const u16* __restrict__ ranks_all,
                                                   const int* __restrict__ rs_all,
                                                   const u32* __restrict__ hist_all,
                                                   u16* __restrict__ csr_all) {
    const int b = blockIdx.x >> 2;
    const int q = blockIdx.x & 3;
    const int t = blockIdx.y;
    const int* src = edges + (size_t)t * 2 * E_EDGES;
    const int* dst = src + E_EDGES;
    const u16* ranks = ranks_all + (size_t)t * (RK_STRIDE / 2);
    const int* row_start = rs_all + (size_t)t * (RS_STRIDE / 4);
    const u32* cs = hist_all + (size_t)t * (HIST_STRIDE / 4) + (size_t)b * NPAIR;
    u16* csr = csr_all + (size_t)t * (CSR_STRIDE / 2);
    const int base = b * CHUNK + q * (CHUNK / 4);
    for (int i = threadIdx.x; i < CHUNK / 4; i += 256) {
        const int d = dst[base + i];
        const int s = src[base + i];
        const int r = ranks[base + i];
        const int off = (int)((cs[d >> 1] >> ((d & 1) * 16)) & 0xFFFFu);
        csr[row_start[d] + off + r] = (u16)s;
    }
}

// One wave per dst node, batched over t via blockIdx.y. fp8 rows (128B);
// half-wave k reads edge 2j+k, lane q=lane&31 holds 4 channels/dword. 8
// edges/iter = 4 independent load instrs in flight (R7 lesson: 1 load/iter
// was latency-bound at 88us; MLP is the fix, bandwidth floor is ~12us).
__global__ __launch_bounds__(256) void gather_kernel(const u32* __restrict__ h8_all,
                                                     const int* __restrict__ rs_all,
                                                     const u16* __restrict__ csr_all,
                                                     float* __restrict__ zp_all) {
    const int lane = threadIdx.x & 63;
    const int wv   = __builtin_amdgcn_readfirstlane((int)(threadIdx.x >> 6));
    const int q    = lane & 31;
    const bool h0  = lane < 32;
    const int o    = h0 ? 0 : 1;            // edge offset within pair
    const int t    = blockIdx.y;
    const u32* h8d = h8_all + (size_t)t * (H_STRIDE / 4);
    const int* row_start = rs_all + (size_t)t * (RS_STRIDE / 4);
    const u16* csr = csr_all + (size_t)t * (CSR_STRIDE / 2);
    float* z_pad = zp_all + (size_t)t * (ZP_STRIDE / 4);
    const int gw   = blockIdx.x * 4 + wv;
    const int nw   = gridDim.x * 4;

    float z0 = 0.f, z1 = 0.f, z2 = 0.f, z3 = 0.f;
    for (int n = gw; n < N_NODES; n += nw) {
        const int rs  = row_start[n];
        const int cnt = row_start[n + 1] - rs;
        // self loop: count once (half 0 only)
        const u32 us = h8d[n * 32 + q];
        const f32x2 slo = __builtin_amdgcn_cvt_pk_f32_fp8(us, 0);
        const f32x2 shi = __builtin_amdgcn_cvt_pk_f32_fp8(us, 1);
        float a0 = h0 ? slo.x : 0.f;
        float a1 = h0 ? slo.y : 0.f;
        float a2 = h0 ? shi.x : 0.f;
        float a3 = h0 ? shi.y : 0.f;

        const u16* lst = csr + rs;
        int i = 0;
        for (; i + 8 <= cnt; i += 8) {       // 4 independent row-pair loads
            const int s0 = lst[i + 0 + o];
            const int s1 = lst[i + 2 + o];
            const int s2 = lst[i + 4 + o];
            const int s3 = lst[i + 6 + o];
            const u32 u0 = h8d[s0 * 32 + q];
            const u32 u1 = h8d[s1 * 32 + q];
            const u32 u2 = h8d[s2 * 32 + q];
            const u32 u3 = h8d[s3 * 32 + q];
            const f32x2 l0 = __builtin_amdgcn_cvt_pk_f32_fp8(u0, 0);
            const f32x2 g0 = __builtin_amdgcn_cvt_pk_f32_fp8(u0, 1);
            const f32x2 l1 = __builtin_amdgcn_cvt_pk_f32_fp8(u1, 0);
            const f32x2 g1 = __builtin_amdgcn_cvt_pk_f32_fp8(u1, 1);
            const f32x2 l2 = __builtin_amdgcn_cvt_pk_f32_fp8(u2, 0);
            const f32x2 g2 = __builtin_amdgcn_cvt_pk_f32_fp8(u2, 1);
            const f32x2 l3 = __builtin_amdgcn_cvt_pk_f32_fp8(u3, 0);
            const f32x2 g3 = __builtin_amdgcn_cvt_pk_f32_fp8(u3, 1);
            a0 += (l0.x + l1.x) + (l2.x + l3.x);
            a1 += (l0.y + l1.y) + (l2.y + l3.y);
            a2 += (g0.x + g1.x) + (g2.x + g3.x);
            a3 += (g0.y + g1.y) + (g2.y + g3.y);
        }
        for (; i + 2 <= cnt; i += 2) {
            const int s = lst[i + o];
            const u32 u = h8d[s * 32 + q];
            const f32x2 lo = __builtin_amdgcn_cvt_pk_f32_fp8(u, 0);
            const f32x2 hi = __builtin_amdgcn_cvt_pk_f32_fp8(u, 1);
            a0 += lo.x; a1 += lo.y; a2 += hi.x; a3 += hi.y;
        }
        if (i < cnt) {                        // odd tail: half 0 only
            const int s = lst[i];
            const u32 u = h8d[s * 32 + q];
            const f32x2 lo = __builtin_amdgcn_cvt_pk_f32_fp8(u, 0);
            const f32x2 hi = __builtin_amdgcn_cvt_pk_f32_fp8(u, 1);
            if (h0) { a0 += lo.x; a1 += lo.y; a2 += hi.x; a3 += hi.y; }
        }
        // combine halves (lane q <-> lane q+32)
        a0 += __shfl_xor(a0, 32);
        a1 += __shfl_xor(a1, 32);
        a2 += __shfl_xor(a2, 32);
        a3 += __shfl_xor(a3, 32);
        const float inv = 1.0f / (float)(cnt + 1);
        z0 += fmaxf(a0 * inv, 0.f);
        z1 += fmaxf(a1 * inv, 0.f);
        z2 += fmaxf(a2 * inv, 0.f);
        z3 += fmaxf(a3 * inv, 0.f);
    }

    // both halves hold identical z -> sum over all 64 lanes counts 2x; scale 0.5
    __shared__ float red[4][64][4];
    red[wv][lane][0] = z0;
    red[wv][lane][1] = z1;
    red[wv][lane][2] = z2;
    red[wv][lane][3] = z3;
    __syncthreads();
    if (threadIdx.x < 128) {
        const int c = threadIdx.x;          // channel
        const int g = c >> 2, m = c & 3;
        float s = 0.f;
#pragma unroll
        for (int w = 0; w < 4; ++w) s += red[w][g][m] + red[w][g + 32][m];
        atomicAdd(&z_pad[c * 32], 0.5f * s);   // 128 slots, 128B apart
    }
}

// All 4 GRU steps + classifier in one block; h lives in LDS the whole time.
__global__ __launch_bounds__(512) void gru_all_kernel(const float* __restrict__ zp_all,
                                                      const float* __restrict__ W_ih,
                                                      const float* __restrict__ W_hh,
                                                      const float* __restrict__ b_ih,
                                                      const float* __restrict__ b_hh,
                                                      const float* __restrict__ W_cls,
                                                      const float* __restrict__ b_cls,
                                                      float* __restrict__ out) {
    __shared__ float zm[128], hs[128], gi[384], gh[384];
    const int tid = threadIdx.x;
    if (tid < 128) hs[tid] = 0.f;
    for (int t = 0; t < T_STEPS; ++t) {
        if (tid < 128)
            zm[tid] = zp_all[(size_t)t * (ZP_STRIDE / 4) + tid * 32] * (1.0f / (float)N_NODES);
        __syncthreads();
        if (tid < 384) {
            float a = b_ih[tid], g = b_hh[tid];
            const float* wi = W_ih + tid * 128;
            const float* wh = W_hh + tid * 128;
#pragma unroll 8
            for (int k = 0; k < 128; ++k) {
                a = fmaf(zm[k], wi[k], a);
                g = fmaf(hs[k], wh[k], g);
            }
            gi[tid] = a;
            gh[tid] = g;
        }
        __syncthreads();
        if (tid < 128) {
            const float r  = 1.f / (1.f + expf(-(gi[tid] + gh[tid])));
            const float zg = 1.f / (1.f + expf(-(gi[128 + tid] + gh[128 + tid])));
            const float ng = tanhf(gi[256 + tid] + r * gh[256 + tid]);
            hs[tid] = (1.f - zg) * ng + zg * hs[tid];
        }
        __syncthreads();
    }
    if (tid < OUT_CH) {
        float a = b_cls[tid];
        const float* wc = W_cls + tid * 128;
#pragma unroll 8
        for (int k = 0; k < 128; ++k) a = fmaf(hs[k], wc[k], a);
        out[tid] = a;
    }
}

extern "C" void kernel_launch(void* const* d_in, const int* in_sizes, int n_in,
                              void* d_out, int out_size, void* d_ws, size_t ws_size,
                              hipStream_t stream) {
    const float* xs    = (const float*)d_in[0];
    const int*   edges = (const int*)d_in[1];
    const float* W_gcn = (const float*)d_in[2];
    const float* b_gcn = (const float*)d_in[3];
    const float* W_ih  = (const float*)d_in[4];
    const float* W_hh  = (const float*)d_in[5];
    const float* b_ih  = (const float*)d_in[6];
    const float* b_hh  = (const float*)d_in[7];
    const float* W_cls = (const float*)d_in[8];
    const float* b_cls = (const float*)d_in[9];
    float* out = (float*)d_out;

    char* ws = (char*)d_ws;
    u8*    h8        = (u8*)(ws + OFF_H);
    int*   deg       = (int*)(ws + OFF_DEG);
    int*   row_start = (int*)(ws + OFF_RS);
    float* z_pad     = (float*)(ws + OFF_ZPAD);
    u16*   csr       = (u16*)(ws + OFF_CSR);
    __bf16* wb       = (__bf16*)(ws + OFF_WB);
    u16*   ranks     = (u16*)(ws + OFF_RANKS);
    u32*   hist      = (u32*)(ws + OFF_HIST);

    // zero all 4 z accumulators + deg tails [50000, 13312*4) per t
    // (ws re-poisoned 0xAA before every launch)
    hipMemsetAsync(z_pad, 0, 4 * ZP_STRIDE, stream);
    for (int t = 0; t < T_STEPS; ++t)
        hipMemsetAsync(ws + OFF_DEG + (size_t)t * DEG_STRIDE + 200000, 0,
                       DEG_STRIDE - 200000, stream);
    wbf_kernel<<<64, 256, 0, stream>>>(W_gcn, wb);

    // batched over all 4 timesteps (grid.y = t); only the GRU is recurrent
    gemm_mfma_kernel<<<dim3(3125, T_STEPS), 256, 0, stream>>>(xs, wb, b_gcn, h8);
    hist_rank_kernel<<<dim3(NB, T_STEPS), 512, 0, stream>>>(edges, hist, ranks);
    colscan_kernel<<<dim3((NPAIR + 255) / 256, T_STEPS), 256, 0, stream>>>(hist, deg);
    scan_kernel<<<dim3(1, T_STEPS), 1024, 0, stream>>>((const int4*)deg, (int4*)row_start);
    fill_kernel<<<dim3(NB * 4, T_STEPS), 256, 0, stream>>>(edges, ranks, row_start, hist, csr);
    gather_kernel<<<dim3(2048, T_STEPS), 256, 0, stream>>>((const u32*)h8, row_start, csr, z_pad);
    gru_all_kernel<<<1, 512, 0, stream>>>(z_pad, W_ih, W_hh, b_ih, b_hh,
                                          W_cls, b_cls, out);
}

// Round 3
// 714.872 us; speedup vs baseline: 1.3086x; 1.0950x over previous
//
#include <hip/hip_runtime.h>
#include <hip/hip_bf16.h>

typedef unsigned int u32;
typedef unsigned short u16;
typedef unsigned char u8;
typedef __attribute__((ext_vector_type(8))) __bf16 bfrag;   // 8 bf16 = 4 VGPRs (MFMA A/B operand)
typedef __attribute__((ext_vector_type(4))) float f32x4;    // MFMA C/D
typedef __attribute__((ext_vector_type(2))) float f32x2;

#define T_STEPS 4
#define N_NODES 50000
#define E_EDGES 1600000
#define HID 128
#define OUT_CH 16

#define NB 128                   // hist blocks; chunk = E/NB
#define CHUNK (E_EDGES / NB)     // 12500
#define NPAIR (N_NODES / 2)      // 25000 packed u16-pair histogram entries
#define SCAN4 13                 // int4s per thread in scan (1024*13=13312 >= 12500)

// ---- workspace layout (bytes); every per-t array has a 256-aligned stride ----
// All 4 timesteps' pipelines are independent (only GRU is recurrent), so each
// array is x4 and kernels batch over t.
#define H_STRIDE    6400000u     // h fp8 [N*128] u8
#define DEG_STRIDE  212992u      // deg [13312 int4 padded]
#define RS_STRIDE   212992u      // row_start [13312 int4]
#define ZP_STRIDE   16384u       // z_sum padded [128*32] f32
#define CSR_STRIDE  3200000u     // csr src [E] u16
#define RK_STRIDE   3200000u     // ranks [E] u16
#define HIST_STRIDE 12800000u    // hist [NB][NPAIR] u32

#define OFF_H     0u                                   // +4*H_STRIDE    = 25,600,000
#define OFF_DEG   25600000u                            // +4*DEG_STRIDE  = 26,451,968
#define OFF_RS    26451968u                            // +4*RS_STRIDE   = 27,303,936
#define OFF_ZPAD  27303936u                            // +4*ZP_STRIDE   = 27,369,472
#define OFF_CSR   27369472u                            // +4*CSR_STRIDE  = 40,169,472
#define OFF_WB    40169984u                            // W_gcn bf16     = 40,202,752
#define OFF_RANKS 40202752u                            // +4*RK_STRIDE   = 53,002,752
#define OFF_HIST  53002752u                            // +4*HIST_STRIDE ~ 104.2 MB (ws >= 409 MB)

__device__ __forceinline__ u8 f32_to_fp8(float v) {
    return (u8)(__builtin_amdgcn_cvt_pk_fp8_f32(v, v, 0, 0) & 0xFF);
}

// one-shot: W fp32 -> bf16 (32 KB, L1-resident for the GEMM)
__global__ void wbf_kernel(const float* __restrict__ W, __bf16* __restrict__ wb) {
    const int i = blockIdx.x * 256 + threadIdx.x;   // 16384
    wb[i] = (__bf16)W[i];
}

// h = fp8(x @ W^T + b) via MFMA 16x16x32 bf16, batched over t (blockIdx.y).
// Frag layouts (m89/m120-verified): A[m=lane&15][k=(lane>>4)*8+j],
// B[n=lane&15][k=(lane>>4)*8+j], C/D row=(lane>>4)*4+reg, col=lane&15.
__global__ __launch_bounds__(256) void gemm_mfma_kernel(const float* __restrict__ xs,
                                                        const __bf16* __restrict__ wb,
                                                        const float* __restrict__ b,
                                                        u8* __restrict__ h8_all) {
    const int lane = threadIdx.x & 63;
    const int wv   = threadIdx.x >> 6;      // 0..3 -> n-slice
    const int r16  = lane & 15;
    const int quad = lane >> 4;
    const int mb   = blockIdx.x;            // rows [16mb, 16mb+16)
    const int t    = blockIdx.y;
    const float* x = xs + (size_t)t * N_NODES * 128;
    u8* h8         = h8_all + (size_t)t * H_STRIDE;

    bfrag Bf[2][4];
#pragma unroll
    for (int nt = 0; nt < 2; ++nt) {
        const int c = wv * 32 + nt * 16 + r16;
#pragma unroll
        for (int ks = 0; ks < 4; ++ks)
            Bf[nt][ks] = *(const bfrag*)(wb + c * 128 + ks * 32 + quad * 8);
    }

    const float* xp = x + (size_t)(mb * 16 + r16) * 128 + quad * 8;
    bfrag Af[4];
#pragma unroll
    for (int ks = 0; ks < 4; ++ks) {
        const float* ap = xp + ks * 32;
#pragma unroll
        for (int j = 0; j < 8; ++j) Af[ks][j] = (__bf16)ap[j];
    }

    f32x4 acc0 = {0.f, 0.f, 0.f, 0.f};
    f32x4 acc1 = {0.f, 0.f, 0.f, 0.f};
#pragma unroll
    for (int ks = 0; ks < 4; ++ks) {
        acc0 = __builtin_amdgcn_mfma_f32_16x16x32_bf16(Af[ks], Bf[0][ks], acc0, 0, 0, 0);
        acc1 = __builtin_amdgcn_mfma_f32_16x16x32_bf16(Af[ks], Bf[1][ks], acc1, 0, 0, 0);
    }

    const int c0 = wv * 32 + r16;
    const float b0 = b[c0], b1 = b[c0 + 16];
#pragma unroll
    for (int r = 0; r < 4; ++r) {
        const size_t row = (size_t)(mb * 16 + quad * 4 + r) * 128;
        h8[row + c0]      = f32_to_fp8(acc0[r] + b0);
        h8[row + c0 + 16] = f32_to_fp8(acc1[r] + b1);
    }
}

// Block (b,t): LDS histogram of its 12500-edge chunk (u16 counts packed 2/u32),
// LDS-atomic return = local rank. No global atomics (R3 lesson: 1.6M
// device-scope atomics = 103 MB EA round-trips).
__global__ __launch_bounds__(512) void hist_rank_kernel(const int* __restrict__ edges,
                                                        u32* __restrict__ hist_all,
                                                        u16* __restrict__ ranks_all) {
    __shared__ u32 hloc[NPAIR / 2];          // 12500 u32 = 50 KB
    const int b = blockIdx.x;
    const int t = blockIdx.y;
    const int* dst = edges + (size_t)t * 2 * E_EDGES + E_EDGES;
    u16* ranks = ranks_all + (size_t)t * (RK_STRIDE / 2);
    const int base = b * CHUNK;
    u32* row = hist_all + (size_t)t * (HIST_STRIDE / 4) + (size_t)b * NPAIR;

#pragma unroll
    for (int half = 0; half < 2; ++half) {
        for (int j = threadIdx.x; j < NPAIR / 2; j += 512) hloc[j] = 0;
        __syncthreads();
        const int jlo = half * (NPAIR / 2);
        for (int i = threadIdx.x; i < CHUNK; i += 512) {
            const int d = dst[base + i];
            const int j = d >> 1;
            if ((j >= jlo) && (j < jlo + NPAIR / 2)) {
                const u32 inc = (d & 1) ? 0x10000u : 1u;
                const u32 old = atomicAdd(&hloc[j - jlo], inc);
                ranks[base + i] = (u16)((old >> ((d & 1) * 16)) & 0xFFFFu);
            }
        }
        __syncthreads();
        for (int j = threadIdx.x; j < NPAIR / 2; j += 512) row[jlo + j] = hloc[j];
        __syncthreads();
    }
}

// In-place exclusive scan over the NB block-rows for each node pair; emits deg.
__global__ void colscan_kernel(u32* __restrict__ hist_all, int* __restrict__ deg_all) {
    const int j = blockIdx.x * blockDim.x + threadIdx.x;
    if (j >= NPAIR) return;
    const int t = blockIdx.y;
    u32 lo = 0, hi = 0;
    u32* p = hist_all + (size_t)t * (HIST_STRIDE / 4) + j;
    int* deg = deg_all + (size_t)t * (DEG_STRIDE / 4);
#pragma unroll 8
    for (int b = 0; b < NB; ++b) {
        const u32 v = p[(size_t)b * NPAIR];
        p[(size_t)b * NPAIR] = lo | (hi << 16);
        lo += v & 0xFFFFu;
        hi += v >> 16;
    }
    deg[2 * j]     = (int)lo;
    deg[2 * j + 1] = (int)hi;
}

// One block per t. Fully unrolled + vectorized (R5 lesson: dynamic-trip
// scalar loops serialize ~100 round-trips). 13 int4/thread, all loads in
// flight before one waitcnt; deg tail pre-zeroed so row_start[50000]=E.
__global__ __launch_bounds__(1024) void scan_kernel(const int4* __restrict__ deg4_all,
                                                    int4* __restrict__ rs4_all) {
    __shared__ int part[1024];
    const int tid = threadIdx.x;
    const int t = blockIdx.y;
    const int4* deg4 = deg4_all + (size_t)t * (DEG_STRIDE / 16);
    int4* rs4 = rs4_all + (size_t)t * (RS_STRIDE / 16);
    int4 v[SCAN4];
#pragma unroll
    for (int j = 0; j < SCAN4; ++j) v[j] = deg4[tid * SCAN4 + j];
    int s = 0;
#pragma unroll
    for (int j = 0; j < SCAN4; ++j) s += v[j].x + v[j].y + v[j].z + v[j].w;
    part[tid] = s;
    __syncthreads();
    for (int d = 1; d < 1024; d <<= 1) {
        const int tmp = (tid >= d) ? part[tid - d] : 0;
        __syncthreads();
        part[tid] += tmp;
        __syncthreads();
    }
    int run = (tid == 0) ? 0 : part[tid - 1];
#pragma unroll
    for (int j = 0; j < SCAN4; ++j) {
        int4 o;
        o.x = run; run += v[j].x;
        o.y = run; run += v[j].y;
        o.z = run; run += v[j].z;
        o.w = run; run += v[j].w;
        rs4[tid * SCAN4 + j] = o;
    }
}

// pos = row_start[d] + colscan[b][d] + local_rank  -- atomic-free CSR fill.
// XCD-pinned: blocks dispatch round-robin over the 8 XCDs, so id&7 selects
// the XCD; t = xcd>>1 gives each timestep a dedicated XCD pair whose 8 MB of
// L2 holds that t's csr (3.2MB) + row_start (200KB) -> scatter-RMW lines
// stay resident until fully written (R1: 17x write inflation without this).
__global__ __launch_bounds__(256) void fill_kernel(const int* __restrict__ edges,
                                                   const u16* __restrict__ ranks_all,
                                                   const int* __restrict__ rs_all,
                                                   const u32* __restrict__ hist_all,
                                                   u16* __restrict__ csr_all) {
    const int id  = blockIdx.x;              // 2048 blocks total
    const int xcd = id & 7;
    const int t   = xcd >> 1;
    const int k   = ((xcd & 1) << 8) | (id >> 3);   // 0..511 within t
    const int b = k >> 2;
    const int q = k & 3;
    const int* src = edges + (size_t)t * 2 * E_EDGES;
    const int* dst = src + E_EDGES;
    const u16* ranks = ranks_all + (size_t)t * (RK_STRIDE / 2);
    const int* row_start = rs_all + (size_t)t * (RS_STRIDE / 4);
    const u32* cs = hist_all + (size_t)t * (HIST_STRIDE / 4) + (size_t)b * NPAIR;
    u16* csr = csr_all + (size_t)t * (CSR_STRIDE / 2);
    const int base = b * CHUNK + q * (CHUNK / 4);
    for (int i = threadIdx.x; i < CHUNK / 4; i += 256) {
        const int d = dst[base + i];
        const int s = src[base + i];
        const int r = ranks[base + i];
        const int off = (int)((cs[d >> 1] >> ((d & 1) * 16)) & 0xFFFFu);
        csr[row_start[d] + off + r] = (u16)s;
    }
}

// One wave per dst node. fp8 rows (128B); half-wave k reads edge 2j+k, lane
// q=lane&31 holds 4 channels/dword. 8 edges/iter = 4 independent load instrs
// in flight (R7 lesson: 1 load/iter was latency-bound at 88us). XCD-pinned
// like fill: each t's h8 (6.4MB) is L2-resident in its XCD pair's 8MB, so
// the random per-edge 128B row reads become L2 hits instead of L3 misses.
__global__ __launch_bounds__(256) void gather_kernel(const u32* __restrict__ h8_all,
                                                     const int* __restrict__ rs_all,
                                                     const u16* __restrict__ csr_all,
                                                     float* __restrict__ zp_all) {
    const int lane = threadIdx.x & 63;
    const int wv   = __builtin_amdgcn_readfirstlane((int)(threadIdx.x >> 6));
    const int q    = lane & 31;
    const bool h0  = lane < 32;
    const int o    = h0 ? 0 : 1;            // edge offset within pair
    const int id   = blockIdx.x;             // 8192 blocks total
    const int xcd  = id & 7;
    const int t    = xcd >> 1;
    const int kb   = ((xcd & 1) << 10) | (id >> 3);  // 0..2047 within t
    const u32* h8d = h8_all + (size_t)t * (H_STRIDE / 4);
    const int* row_start = rs_all + (size_t)t * (RS_STRIDE / 4);
    const u16* csr = csr_all + (size_t)t * (CSR_STRIDE / 2);
    float* z_pad = zp_all + (size_t)t * (ZP_STRIDE / 4);
    const int gw   = kb * 4 + wv;
    const int nw   = 2048 * 4;              // waves per timestep

    float z0 = 0.f, z1 = 0.f, z2 = 0.f, z3 = 0.f;
    for (int n = gw; n < N_NODES; n += nw) {
        const int rs  = row_start[n];
        const int cnt = row_start[n + 1] - rs;
        // self loop: count once (half 0 only)
        const u32 us = h8d[n * 32 + q];
        const f32x2 slo = __builtin_amdgcn_cvt_pk_f32_fp8(us, 0);
        const f32x2 shi = __builtin_amdgcn_cvt_pk_f32_fp8(us, 1);
        float a0 = h0 ? slo.x : 0.f;
        float a1 = h0 ? slo.y : 0.f;
        float a2 = h0 ? shi.x : 0.f;
        float a3 = h0 ? shi.y : 0.f;

        const u16* lst = csr + rs;
        int i = 0;
        for (; i + 8 <= cnt; i += 8) {       // 4 independent row-pair loads
            const int s0 = lst[i + 0 + o];
            const int s1 = lst[i + 2 + o];
            const int s2 = lst[i + 4 + o];
            const int s3 = lst[i + 6 + o];
            const u32 u0 = h8d[s0 * 32 + q];
            const u32 u1 = h8d[s1 * 32 + q];
            const u32 u2 = h8d[s2 * 32 + q];
            const u32 u3 = h8d[s3 * 32 + q];
            const f32x2 l0 = __builtin_amdgcn_cvt_pk_f32_fp8(u0, 0);
            const f32x2 g0 = __builtin_amdgcn_cvt_pk_f32_fp8(u0, 1);
            const f32x2 l1 = __builtin_amdgcn_cvt_pk_f32_fp8(u1, 0);
            const f32x2 g1 = __builtin_amdgcn_cvt_pk_f32_fp8(u1, 1);
            const f32x2 l2 = __builtin_amdgcn_cvt_pk_f32_fp8(u2, 0);
            const f32x2 g2 = __builtin_amdgcn_cvt_pk_f32_fp8(u2, 1);
            const f32x2 l3 = __builtin_amdgcn_cvt_pk_f32_fp8(u3, 0);
            const f32x2 g3 = __builtin_amdgcn_cvt_pk_f32_fp8(u3, 1);
            a0 += (l0.x + l1.x) + (l2.x + l3.x);
            a1 += (l0.y + l1.y) + (l2.y + l3.y);
            a2 += (g0.x + g1.x) + (g2.x + g3.x);
            a3 += (g0.y + g1.y) + (g2.y + g3.y);
        }
        for (; i + 2 <= cnt; i += 2) {
            const int s = lst[i + o];
            const u32 u = h8d[s * 32 + q];
            const f32x2 lo = __builtin_amdgcn_cvt_pk_f32_fp8(u, 0);
            const f32x2 hi = __builtin_amdgcn_cvt_pk_f32_fp8(u, 1);
            a0 += lo.x; a1 += lo.y; a2 += hi.x; a3 += hi.y;
        }
        if (i < cnt) {                        // odd tail: half 0 only
            const int s = lst[i];
            const u32 u = h8d[s * 32 + q];
            const f32x2 lo = __builtin_amdgcn_cvt_pk_f32_fp8(u, 0);
            const f32x2 hi = __builtin_amdgcn_cvt_pk_f32_fp8(u, 1);
            if (h0) { a0 += lo.x; a1 += lo.y; a2 += hi.x; a3 += hi.y; }
        }
        // combine halves (lane q <-> lane q+32)
        a0 += __shfl_xor(a0, 32);
        a1 += __shfl_xor(a1, 32);
        a2 += __shfl_xor(a2, 32);
        a3 += __shfl_xor(a3, 32);
        const float inv = 1.0f / (float)(cnt + 1);
        z0 += fmaxf(a0 * inv, 0.f);
        z1 += fmaxf(a1 * inv, 0.f);
        z2 += fmaxf(a2 * inv, 0.f);
        z3 += fmaxf(a3 * inv, 0.f);
    }

    // both halves hold identical z -> sum over all 64 lanes counts 2x; scale 0.5
    __shared__ float red[4][64][4];
    red[wv][lane][0] = z0;
    red[wv][lane][1] = z1;
    red[wv][lane][2] = z2;
    red[wv][lane][3] = z3;
    __syncthreads();
    if (threadIdx.x < 128) {
        const int c = threadIdx.x;          // channel
        const int g = c >> 2, m = c & 3;
        float s = 0.f;
#pragma unroll
        for (int w = 0; w < 4; ++w) s += red[w][g][m] + red[w][g + 32][m];
        atomicAdd(&z_pad[c * 32], 0.5f * s);   // 128 slots, 128B apart
    }
}

// All 4 GRU steps + classifier in one block; h lives in LDS the whole time.
__global__ __launch_bounds__(512) void gru_all_kernel(const float* __restrict__ zp_all,
                                                      const float* __restrict__ W_ih,
                                                      const float* __restrict__ W_hh,
                                                      const float* __restrict__ b_ih,
                                                      const float* __restrict__ b_hh,
                                                      const float* __restrict__ W_cls,
                                                      const float* __restrict__ b_cls,
                                                      float* __restrict__ out) {
    __shared__ float zm[128], hs[128], gi[384], gh[384];
    const int tid = threadIdx.x;
    if (tid < 128) hs[tid] = 0.f;
    for (int t = 0; t < T_STEPS; ++t) {
        if (tid < 128)
            zm[tid] = zp_all[(size_t)t * (ZP_STRIDE / 4) + tid * 32] * (1.0f / (float)N_NODES);
        __syncthreads();
        if (tid < 384) {
            float a = b_ih[tid], g = b_hh[tid];
            const float* wi = W_ih + tid * 128;
            const float* wh = W_hh + tid * 128;
#pragma unroll 8
            for (int k = 0; k < 128; ++k) {
                a = fmaf(zm[k], wi[k], a);
                g = fmaf(hs[k], wh[k], g);
            }
            gi[tid] = a;
            gh[tid] = g;
        }
        __syncthreads();
        if (tid < 128) {
            const float r  = 1.f / (1.f + expf(-(gi[tid] + gh[tid])));
            const float zg = 1.f / (1.f + expf(-(gi[128 + tid] + gh[128 + tid])));
            const float ng = tanhf(gi[256 + tid] + r * gh[256 + tid]);
            hs[tid] = (1.f - zg) * ng + zg * hs[tid];
        }
        __syncthreads();
    }
    if (tid < OUT_CH) {
        float a = b_cls[tid];
        const float* wc = W_cls + tid * 128;
#pragma unroll 8
        for (int k = 0; k < 128; ++k) a = fmaf(hs[k], wc[k], a);
        out[tid] = a;
    }
}

extern "C" void kernel_launch(void* const* d_in, const int* in_sizes, int n_in,
                              void* d_out, int out_size, void* d_ws, size_t ws_size,
                              hipStream_t stream) {
    const float* xs    = (const float*)d_in[0];
    const int*   edges = (const int*)d_in[1];
    const float* W_gcn = (const float*)d_in[2];
    const float* b_gcn = (const float*)d_in[3];
    const float* W_ih  = (const float*)d_in[4];
    const float* W_hh  = (const float*)d_in[5];
    const float* b_ih  = (const float*)d_in[6];
    const float* b_hh  = (const float*)d_in[7];
    const float* W_cls = (const float*)d_in[8];
    const float* b_cls = (const float*)d_in[9];
    float* out = (float*)d_out;

    char* ws = (char*)d_ws;
    u8*    h8        = (u8*)(ws + OFF_H);
    int*   deg       = (int*)(ws + OFF_DEG);
    int*   row_start = (int*)(ws + OFF_RS);
    float* z_pad     = (float*)(ws + OFF_ZPAD);
    u16*   csr       = (u16*)(ws + OFF_CSR);
    __bf16* wb       = (__bf16*)(ws + OFF_WB);
    u16*   ranks     = (u16*)(ws + OFF_RANKS);
    u32*   hist      = (u32*)(ws + OFF_HIST);

    // zero all 4 z accumulators + deg tails [50000, 13312*4) per t
    // (ws re-poisoned 0xAA before every launch)
    hipMemsetAsync(z_pad, 0, 4 * ZP_STRIDE, stream);
    for (int t = 0; t < T_STEPS; ++t)
        hipMemsetAsync(ws + OFF_DEG + (size_t)t * DEG_STRIDE + 200000, 0,
                       DEG_STRIDE - 200000, stream);
    wbf_kernel<<<64, 256, 0, stream>>>(W_gcn, wb);

    // batched over all 4 timesteps; only the GRU is recurrent
    gemm_mfma_kernel<<<dim3(3125, T_STEPS), 256, 0, stream>>>(xs, wb, b_gcn, h8);
    hist_rank_kernel<<<dim3(NB, T_STEPS), 512, 0, stream>>>(edges, hist, ranks);
    colscan_kernel<<<dim3((NPAIR + 255) / 256, T_STEPS), 256, 0, stream>>>(hist, deg);
    scan_kernel<<<dim3(1, T_STEPS), 1024, 0, stream>>>((const int4*)deg, (int4*)row_start);
    fill_kernel<<<NB * 4 * T_STEPS, 256, 0, stream>>>(edges, ranks, row_start, hist, csr);
    gather_kernel<<<2048 * T_STEPS, 256, 0, stream>>>((const u32*)h8, row_start, csr, z_pad);
    gru_all_kernel<<<1, 512, 0, stream>>>(z_pad, W_ih, W_hh, b_ih, b_hh,
                                          W_cls, b_cls, out);
}

// Round 4
// 698.921 us; speedup vs baseline: 1.3385x; 1.0228x over previous
//
#include <hip/hip_runtime.h>
#include <hip/hip_bf16.h>

typedef unsigned int u32;
typedef unsigned short u16;
typedef unsigned char u8;
typedef __attribute__((ext_vector_type(8))) __bf16 bfrag;   // 8 bf16 = 4 VGPRs (MFMA A/B operand)
typedef __attribute__((ext_vector_type(4))) float f32x4;    // MFMA C/D
typedef __attribute__((ext_vector_type(2))) float f32x2;

#define T_STEPS 4
#define N_NODES 50000
#define E_EDGES 1600000
#define HID 128
#define OUT_CH 16

#define NB 128                   // hist blocks; chunk = E/NB
#define CHUNK (E_EDGES / NB)     // 12500
#define NPAIR (N_NODES / 2)      // 25000 packed u16-pair histogram entries
#define SCAN4 13                 // int4s per thread in scan (1024*13=13312 >= 12500)

// ---- workspace layout (bytes); every per-t array has a 256-aligned stride ----
// All 4 timesteps' pipelines are independent (only GRU is recurrent), so each
// array is x4 and kernels batch over t.
#define H_STRIDE    6400000u     // h fp8 [N*128] u8
#define DEG_STRIDE  212992u      // deg [13312 int4 padded]
#define RS_STRIDE   212992u      // row_start [13312 int4]
#define ZP_STRIDE   16384u       // z_sum padded [128*32] f32
#define CSR_STRIDE  3200000u     // csr src [E] u16
#define RK_STRIDE   3200000u     // ranks [E] u16
#define HIST_STRIDE 12800000u    // hist [NB][NPAIR] u32

#define OFF_H     0u                                   // +4*H_STRIDE    = 25,600,000
#define OFF_DEG   25600000u                            // +4*DEG_STRIDE  = 26,451,968
#define OFF_RS    26451968u                            // +4*RS_STRIDE   = 27,303,936
#define OFF_ZPAD  27303936u                            // +4*ZP_STRIDE   = 27,369,472
#define OFF_CSR   27369472u                            // +4*CSR_STRIDE  = 40,169,472
#define OFF_WB    40169984u                            // W_gcn bf16     = 40,202,752
#define OFF_RANKS 40202752u                            // +4*RK_STRIDE   = 53,002,752
#define OFF_HIST  53002752u                            // +4*HIST_STRIDE ~ 104.2 MB (ws >= 409 MB)

__device__ __forceinline__ u8 f32_to_fp8(float v) {
    return (u8)(__builtin_amdgcn_cvt_pk_fp8_f32(v, v, 0, 0) & 0xFF);
}

// one-shot: W fp32 -> bf16 (32 KB, L1-resident for the GEMM)
__global__ void wbf_kernel(const float* __restrict__ W, __bf16* __restrict__ wb) {
    const int i = blockIdx.x * 256 + threadIdx.x;   // 16384
    wb[i] = (__bf16)W[i];
}

// h = fp8(x @ W^T + b) via MFMA 16x16x32 bf16, batched over t (blockIdx.y).
// Frag layouts (m89/m120-verified): A[m=lane&15][k=(lane>>4)*8+j],
// B[n=lane&15][k=(lane>>4)*8+j], C/D row=(lane>>4)*4+reg, col=lane&15.
__global__ __launch_bounds__(256) void gemm_mfma_kernel(const float* __restrict__ xs,
                                                        const __bf16* __restrict__ wb,
                                                        const float* __restrict__ b,
                                                        u8* __restrict__ h8_all) {
    const int lane = threadIdx.x & 63;
    const int wv   = threadIdx.x >> 6;      // 0..3 -> n-slice
    const int r16  = lane & 15;
    const int quad = lane >> 4;
    const int mb   = blockIdx.x;            // rows [16mb, 16mb+16)
    const int t    = blockIdx.y;
    const float* x = xs + (size_t)t * N_NODES * 128;
    u8* h8         = h8_all + (size_t)t * H_STRIDE;

    bfrag Bf[2][4];
#pragma unroll
    for (int nt = 0; nt < 2; ++nt) {
        const int c = wv * 32 + nt * 16 + r16;
#pragma unroll
        for (int ks = 0; ks < 4; ++ks)
            Bf[nt][ks] = *(const bfrag*)(wb + c * 128 + ks * 32 + quad * 8);
    }

    const float* xp = x + (size_t)(mb * 16 + r16) * 128 + quad * 8;
    bfrag Af[4];
#pragma unroll
    for (int ks = 0; ks < 4; ++ks) {
        const float* ap = xp + ks * 32;
#pragma unroll
        for (int j = 0; j < 8; ++j) Af[ks][j] = (__bf16)ap[j];
    }

    f32x4 acc0 = {0.f, 0.f, 0.f, 0.f};
    f32x4 acc1 = {0.f, 0.f, 0.f, 0.f};
#pragma unroll
    for (int ks = 0; ks < 4; ++ks) {
        acc0 = __builtin_amdgcn_mfma_f32_16x16x32_bf16(Af[ks], Bf[0][ks], acc0, 0, 0, 0);
        acc1 = __builtin_amdgcn_mfma_f32_16x16x32_bf16(Af[ks], Bf[1][ks], acc1, 0, 0, 0);
    }

    const int c0 = wv * 32 + r16;
    const float b0 = b[c0], b1 = b[c0 + 16];
#pragma unroll
    for (int r = 0; r < 4; ++r) {
        const size_t row = (size_t)(mb * 16 + quad * 4 + r) * 128;
        h8[row + c0]      = f32_to_fp8(acc0[r] + b0);
        h8[row + c0 + 16] = f32_to_fp8(acc1[r] + b1);
    }
}

// Block (b,t): LDS histogram of its 12500-edge chunk (u16 counts packed 2/u32),
// LDS-atomic return = local rank. No global atomics (R3 lesson: 1.6M
// device-scope atomics = 103 MB EA round-trips).
__global__ __launch_bounds__(512) void hist_rank_kernel(const int* __restrict__ edges,
                                                        u32* __restrict__ hist_all,
                                                        u16* __restrict__ ranks_all) {
    __shared__ u32 hloc[NPAIR / 2];          // 12500 u32 = 50 KB
    const int b = blockIdx.x;
    const int t = blockIdx.y;
    const int* dst = edges + (size_t)t * 2 * E_EDGES + E_EDGES;
    u16* ranks = ranks_all + (size_t)t * (RK_STRIDE / 2);
    const int base = b * CHUNK;
    u32* row = hist_all + (size_t)t * (HIST_STRIDE / 4) + (size_t)b * NPAIR;

#pragma unroll
    for (int half = 0; half < 2; ++half) {
        for (int j = threadIdx.x; j < NPAIR / 2; j += 512) hloc[j] = 0;
        __syncthreads();
        const int jlo = half * (NPAIR / 2);
        for (int i = threadIdx.x; i < CHUNK; i += 512) {
            const int d = dst[base + i];
            const int j = d >> 1;
            if ((j >= jlo) && (j < jlo + NPAIR / 2)) {
                const u32 inc = (d & 1) ? 0x10000u : 1u;
                const u32 old = atomicAdd(&hloc[j - jlo], inc);
                ranks[base + i] = (u16)((old >> ((d & 1) * 16)) & 0xFFFFu);
            }
        }
        __syncthreads();
        for (int j = threadIdx.x; j < NPAIR / 2; j += 512) row[jlo + j] = hloc[j];
        __syncthreads();
    }
}

// In-place exclusive scan over the NB block-rows for each node pair; emits deg.
__global__ void colscan_kernel(u32* __restrict__ hist_all, int* __restrict__ deg_all) {
    const int j = blockIdx.x * blockDim.x + threadIdx.x;
    if (j >= NPAIR) return;
    const int t = blockIdx.y;
    u32 lo = 0, hi = 0;
    u32* p = hist_all + (size_t)t * (HIST_STRIDE / 4) + j;
    int* deg = deg_all + (size_t)t * (DEG_STRIDE / 4);
#pragma unroll 8
    for (int b = 0; b < NB; ++b) {
        const u32 v = p[(size_t)b * NPAIR];
        p[(size_t)b * NPAIR] = lo | (hi << 16);
        lo += v & 0xFFFFu;
        hi += v >> 16;
    }
    deg[2 * j]     = (int)lo;
    deg[2 * j + 1] = (int)hi;
}

// One block per t. Fully unrolled + vectorized (R5 lesson: dynamic-trip
// scalar loops serialize ~100 round-trips). 13 int4/thread, all loads in
// flight before one waitcnt; deg tail pre-zeroed so row_start[50000]=E.
__global__ __launch_bounds__(1024) void scan_kernel(const int4* __restrict__ deg4_all,
                                                    int4* __restrict__ rs4_all) {
    __shared__ int part[1024];
    const int tid = threadIdx.x;
    const int t = blockIdx.y;
    const int4* deg4 = deg4_all + (size_t)t * (DEG_STRIDE / 16);
    int4* rs4 = rs4_all + (size_t)t * (RS_STRIDE / 16);
    int4 v[SCAN4];
#pragma unroll
    for (int j = 0; j < SCAN4; ++j) v[j] = deg4[tid * SCAN4 + j];
    int s = 0;
#pragma unroll
    for (int j = 0; j < SCAN4; ++j) s += v[j].x + v[j].y + v[j].z + v[j].w;
    part[tid] = s;
    __syncthreads();
    for (int d = 1; d < 1024; d <<= 1) {
        const int tmp = (tid >= d) ? part[tid - d] : 0;
        __syncthreads();
        part[tid] += tmp;
        __syncthreads();
    }
    int run = (tid == 0) ? 0 : part[tid - 1];
#pragma unroll
    for (int j = 0; j < SCAN4; ++j) {
        int4 o;
        o.x = run; run += v[j].x;
        o.y = run; run += v[j].y;
        o.z = run; run += v[j].z;
        o.w = run; run += v[j].w;
        rs4[tid * SCAN4 + j] = o;
    }
}

// pos = row_start[d] + colscan[b][d] + local_rank  -- atomic-free CSR fill.
// XCD-pinned + single-writer: t = (id&7)>>1 pins each timestep to an XCD
// pair (validated R3: FETCH 381->181 MB). NEW (R4): within the pair, each
// XCD owns HALF the dst-node range and writes only those edges -- every csr
// line is written by exactly ONE L2 (1.6 MB resident in 4 MB), killing the
// 17x write-back inflation (225 MB vs 12.8 MB payload) caused by lines
// partially dirty in two non-coherent L2s. Streams (dst/src/ranks) are read
// twice (~+35 MB) -- cheap sequential traffic.
__global__ __launch_bounds__(256) void fill_kernel(const int* __restrict__ edges,
                                                   const u16* __restrict__ ranks_all,
                                                   const int* __restrict__ rs_all,
                                                   const u32* __restrict__ hist_all,
                                                   u16* __restrict__ csr_all) {
    const int id   = blockIdx.x;             // 2048 blocks total
    const int xcd  = id & 7;
    const int t    = xcd >> 1;
    const int half = xcd & 1;                // dst-node half owned by this XCD
    const int k    = id >> 3;                // 0..255 within (t)
    const int b    = k >> 1;                 // hist chunk row 0..127
    const int sub  = k & 1;                  // half-chunk 0..1
    const int nlo  = half * (N_NODES / 2);
    const int nhi  = nlo + N_NODES / 2;
    const int* src = edges + (size_t)t * 2 * E_EDGES;
    const int* dst = src + E_EDGES;
    const u16* ranks = ranks_all + (size_t)t * (RK_STRIDE / 2);
    const int* row_start = rs_all + (size_t)t * (RS_STRIDE / 4);
    const u32* cs = hist_all + (size_t)t * (HIST_STRIDE / 4) + (size_t)b * NPAIR;
    u16* csr = csr_all + (size_t)t * (CSR_STRIDE / 2);
    const int base = b * CHUNK + sub * (CHUNK / 2);
    for (int i = threadIdx.x; i < CHUNK / 2; i += 256) {
        const int d = dst[base + i];
        if (d >= nlo && d < nhi) {
            const int s = src[base + i];
            const int r = ranks[base + i];
            const int off = (int)((cs[d >> 1] >> ((d & 1) * 16)) & 0xFFFFu);
            csr[row_start[d] + off + r] = (u16)s;
        }
    }
}

// One wave per dst node. fp8 rows (128B); half-wave k reads edge 2j+k, lane
// q=lane&31 holds 4 channels/dword. 8 edges/iter = 4 independent load instrs
// in flight (R7 lesson: 1 load/iter was latency-bound at 88us). XCD-pinned
// like fill: each t's h8 (6.4MB) is L2-resident in its XCD pair's 8MB, so
// the random per-edge 128B row reads become L2 hits instead of L3 misses.
__global__ __launch_bounds__(256) void gather_kernel(const u32* __restrict__ h8_all,
                                                     const int* __restrict__ rs_all,
                                                     const u16* __restrict__ csr_all,
                                                     float* __restrict__ zp_all) {
    const int lane = threadIdx.x & 63;
    const int wv   = __builtin_amdgcn_readfirstlane((int)(threadIdx.x >> 6));
    const int q    = lane & 31;
    const bool h0  = lane < 32;
    const int o    = h0 ? 0 : 1;            // edge offset within pair
    const int id   = blockIdx.x;             // 8192 blocks total
    const int xcd  = id & 7;
    const int t    = xcd >> 1;
    const int kb   = ((xcd & 1) << 10) | (id >> 3);  // 0..2047 within t
    const u32* h8d = h8_all + (size_t)t * (H_STRIDE / 4);
    const int* row_start = rs_all + (size_t)t * (RS_STRIDE / 4);
    const u16* csr = csr_all + (size_t)t * (CSR_STRIDE / 2);
    float* z_pad = zp_all + (size_t)t * (ZP_STRIDE / 4);
    const int gw   = kb * 4 + wv;
    const int nw   = 2048 * 4;              // waves per timestep

    float z0 = 0.f, z1 = 0.f, z2 = 0.f, z3 = 0.f;
    for (int n = gw; n < N_NODES; n += nw) {
        const int rs  = row_start[n];
        const int cnt = row_start[n + 1] - rs;
        // self loop: count once (half 0 only)
        const u32 us = h8d[n * 32 + q];
        const f32x2 slo = __builtin_amdgcn_cvt_pk_f32_fp8(us, 0);
        const f32x2 shi = __builtin_amdgcn_cvt_pk_f32_fp8(us, 1);
        float a0 = h0 ? slo.x : 0.f;
        float a1 = h0 ? slo.y : 0.f;
        float a2 = h0 ? shi.x : 0.f;
        float a3 = h0 ? shi.y : 0.f;

        const u16* lst = csr + rs;
        int i = 0;
        for (; i + 8 <= cnt; i += 8) {       // 4 independent row-pair loads
            const int s0 = lst[i + 0 + o];
            const int s1 = lst[i + 2 + o];
            const int s2 = lst[i + 4 + o];
            const int s3 = lst[i + 6 + o];
            const u32 u0 = h8d[s0 * 32 + q];
            const u32 u1 = h8d[s1 * 32 + q];
            const u32 u2 = h8d[s2 * 32 + q];
            const u32 u3 = h8d[s3 * 32 + q];
            const f32x2 l0 = __builtin_amdgcn_cvt_pk_f32_fp8(u0, 0);
            const f32x2 g0 = __builtin_amdgcn_cvt_pk_f32_fp8(u0, 1);
            const f32x2 l1 = __builtin_amdgcn_cvt_pk_f32_fp8(u1, 0);
            const f32x2 g1 = __builtin_amdgcn_cvt_pk_f32_fp8(u1, 1);
            const f32x2 l2 = __builtin_amdgcn_cvt_pk_f32_fp8(u2, 0);
            const f32x2 g2 = __builtin_amdgcn_cvt_pk_f32_fp8(u2, 1);
            const f32x2 l3 = __builtin_amdgcn_cvt_pk_f32_fp8(u3, 0);
            const f32x2 g3 = __builtin_amdgcn_cvt_pk_f32_fp8(u3, 1);
            a0 += (l0.x + l1.x) + (l2.x + l3.x);
            a1 += (l0.y + l1.y) + (l2.y + l3.y);
            a2 += (g0.x + g1.x) + (g2.x + g3.x);
            a3 += (g0.y + g1.y) + (g2.y + g3.y);
        }
        for (; i + 2 <= cnt; i += 2) {
            const int s = lst[i + o];
            const u32 u = h8d[s * 32 + q];
            const f32x2 lo = __builtin_amdgcn_cvt_pk_f32_fp8(u, 0);
            const f32x2 hi = __builtin_amdgcn_cvt_pk_f32_fp8(u, 1);
            a0 += lo.x; a1 += lo.y; a2 += hi.x; a3 += hi.y;
        }
        if (i < cnt) {                        // odd tail: half 0 only
            const int s = lst[i];
            const u32 u = h8d[s * 32 + q];
            const f32x2 lo = __builtin_amdgcn_cvt_pk_f32_fp8(u, 0);
            const f32x2 hi = __builtin_amdgcn_cvt_pk_f32_fp8(u, 1);
            if (h0) { a0 += lo.x; a1 += lo.y; a2 += hi.x; a3 += hi.y; }
        }
        // combine halves (lane q <-> lane q+32)
        a0 += __shfl_xor(a0, 32);
        a1 += __shfl_xor(a1, 32);
        a2 += __shfl_xor(a2, 32);
        a3 += __shfl_xor(a3, 32);
        const float inv = 1.0f / (float)(cnt + 1);
        z0 += fmaxf(a0 * inv, 0.f);
        z1 += fmaxf(a1 * inv, 0.f);
        z2 += fmaxf(a2 * inv, 0.f);
        z3 += fmaxf(a3 * inv, 0.f);
    }

    // both halves hold identical z -> sum over all 64 lanes counts 2x; scale 0.5
    __shared__ float red[4][64][4];
    red[wv][lane][0] = z0;
    red[wv][lane][1] = z1;
    red[wv][lane][2] = z2;
    red[wv][lane][3] = z3;
    __syncthreads();
    if (threadIdx.x < 128) {
        const int c = threadIdx.x;          // channel
        const int g = c >> 2, m = c & 3;
        float s = 0.f;
#pragma unroll
        for (int w = 0; w < 4; ++w) s += red[w][g][m] + red[w][g + 32][m];
        atomicAdd(&z_pad[c * 32], 0.5f * s);   // 128 slots, 128B apart
    }
}

// All 4 GRU steps + classifier in one block; h lives in LDS the whole time.
__global__ __launch_bounds__(512) void gru_all_kernel(const float* __restrict__ zp_all,
                                                      const float* __restrict__ W_ih,
                                                      const float* __restrict__ W_hh,
                                                      const float* __restrict__ b_ih,
                                                      const float* __restrict__ b_hh,
                                                      const float* __restrict__ W_cls,
                                                      const float* __restrict__ b_cls,
                                                      float* __restrict__ out) {
    __shared__ float zm[128], hs[128], gi[384], gh[384];
    const int tid = threadIdx.x;
    if (tid < 128) hs[tid] = 0.f;
    for (int t = 0; t < T_STEPS; ++t) {
        if (tid < 128)
            zm[tid] = zp_all[(size_t)t * (ZP_STRIDE / 4) + tid * 32] * (1.0f / (float)N_NODES);
        __syncthreads();
        if (tid < 384) {
            float a = b_ih[tid], g = b_hh[tid];
            const float* wi = W_ih + tid * 128;
            const float* wh = W_hh + tid * 128;
#pragma unroll 8
            for (int k = 0; k < 128; ++k) {
                a = fmaf(zm[k], wi[k], a);
                g = fmaf(hs[k], wh[k], g);
            }
            gi[tid] = a;
            gh[tid] = g;
        }
        __syncthreads();
        if (tid < 128) {
            const float r  = 1.f / (1.f + expf(-(gi[tid] + gh[tid])));
            const float zg = 1.f / (1.f + expf(-(gi[128 + tid] + gh[128 + tid])));
            const float ng = tanhf(gi[256 + tid] + r * gh[256 + tid]);
            hs[tid] = (1.f - zg) * ng + zg * hs[tid];
        }
        __syncthreads();
    }
    if (tid < OUT_CH) {
        float a = b_cls[tid];
        const float* wc = W_cls + tid * 128;
#pragma unroll 8
        for (int k = 0; k < 128; ++k) a = fmaf(hs[k], wc[k], a);
        out[tid] = a;
    }
}

extern "C" void kernel_launch(void* const* d_in, const int* in_sizes, int n_in,
                              void* d_out, int out_size, void* d_ws, size_t ws_size,
                              hipStream_t stream) {
    const float* xs    = (const float*)d_in[0];
    const int*   edges = (const int*)d_in[1];
    const float* W_gcn = (const float*)d_in[2];
    const float* b_gcn = (const float*)d_in[3];
    const float* W_ih  = (const float*)d_in[4];
    const float* W_hh  = (const float*)d_in[5];
    const float* b_ih  = (const float*)d_in[6];
    const float* b_hh  = (const float*)d_in[7];
    const float* W_cls = (const float*)d_in[8];
    const float* b_cls = (const float*)d_in[9];
    float* out = (float*)d_out;

    char* ws = (char*)d_ws;
    u8*    h8        = (u8*)(ws + OFF_H);
    int*   deg       = (int*)(ws + OFF_DEG);
    int*   row_start = (int*)(ws + OFF_RS);
    float* z_pad     = (float*)(ws + OFF_ZPAD);
    u16*   csr       = (u16*)(ws + OFF_CSR);
    __bf16* wb       = (__bf16*)(ws + OFF_WB);
    u16*   ranks     = (u16*)(ws + OFF_RANKS);
    u32*   hist      = (u32*)(ws + OFF_HIST);

    // zero all 4 z accumulators + deg tails [50000, 13312*4) per t
    // (ws re-poisoned 0xAA before every launch)
    hipMemsetAsync(z_pad, 0, 4 * ZP_STRIDE, stream);
    for (int t = 0; t < T_STEPS; ++t)
        hipMemsetAsync(ws + OFF_DEG + (size_t)t * DEG_STRIDE + 200000, 0,
                       DEG_STRIDE - 200000, stream);
    wbf_kernel<<<64, 256, 0, stream>>>(W_gcn, wb);

    // batched over all 4 timesteps; only the GRU is recurrent
    gemm_mfma_kernel<<<dim3(3125, T_STEPS), 256, 0, stream>>>(xs, wb, b_gcn, h8);
    hist_rank_kernel<<<dim3(NB, T_STEPS), 512, 0, stream>>>(edges, hist, ranks);
    colscan_kernel<<<dim3((NPAIR + 255) / 256, T_STEPS), 256, 0, stream>>>(hist, deg);
    scan_kernel<<<dim3(1, T_STEPS), 1024, 0, stream>>>((const int4*)deg, (int4*)row_start);
    fill_kernel<<<NB * 4 * T_STEPS, 256, 0, stream>>>(edges, ranks, row_start, hist, csr);
    gather_kernel<<<2048 * T_STEPS, 256, 0, stream>>>((const u32*)h8, row_start, csr, z_pad);
    gru_all_kernel<<<1, 512, 0, stream>>>(z_pad, W_ih, W_hh, b_ih, b_hh,
                                          W_cls, b_cls, out);
}

// Round 5
// 568.153 us; speedup vs baseline: 1.6466x; 1.2302x over previous
//
#include <hip/hip_runtime.h>
#include <hip/hip_bf16.h>

typedef unsigned int u32;
typedef unsigned short u16;
typedef unsigned char u8;
typedef __attribute__((ext_vector_type(8))) __bf16 bfrag;   // 8 bf16 = 4 VGPRs (MFMA A/B operand)
typedef __attribute__((ext_vector_type(4))) float f32x4;    // MFMA C/D
typedef __attribute__((ext_vector_type(2))) float f32x2;

#define T_STEPS 4
#define N_NODES 50000
#define E_EDGES 1600000
#define HID 128
#define OUT_CH 16

#define NCHUNK 128               // partition blocks per t; chunk = E/NCHUNK
#define CHUNK (E_EDGES / NCHUNK) // 12500
#define NBKT 196                 // dst buckets per t (256 nodes each: bkt = d>>8)
#define BCAP 10240               // records per bucket region (mean 8192, sigma~90 -> 22 sigma)

// ---- workspace layout (bytes); per-t arrays have 256-aligned strides ----
// All 4 timesteps' pipelines are independent (only GRU is recurrent).
// R5 redesign: CSR built via bucket partition (196 buckets x 256 nodes).
// ranks/hist/colscan/scan deleted -- order within a node's list is
// irrelevant to the gather sum.
#define H_STRIDE    6400000u     // h fp8 [N*128] u8
#define RS_STRIDE   204800u      // row_start [51200 int] (need 50001)
#define ZP_STRIDE   16384u       // z_sum padded [128*32] f32
#define CSR_STRIDE  3200000u     // csr src [E] u16

#define OFF_H     0u             // +4*H_STRIDE  = 25,600,000
#define OFF_RS    25600000u      // +4*RS_STRIDE = 26,419,200
#define OFF_ZPAD  26419200u      // +4*ZP_STRIDE = 26,484,736
#define OFF_CSR   26484736u      // +4*CSR      = 39,284,736
#define OFF_WB    39284736u      // W_gcn bf16  = 39,317,504
#define OFF_GCNT  39317504u      // gcnt [4][256] u32 = 39,321,600
#define OFF_BBASE 39321600u      // bbase [4][256] u32 = 39,325,696
#define OFF_RECS  39325696u      // recs [4][196][BCAP] u32 -> ends ~71.4 MB

__device__ __forceinline__ u8 f32_to_fp8(float v) {
    return (u8)(__builtin_amdgcn_cvt_pk_fp8_f32(v, v, 0, 0) & 0xFF);
}

// one-shot: W fp32 -> bf16 (32 KB, L1-resident for the GEMM)
__global__ void wbf_kernel(const float* __restrict__ W, __bf16* __restrict__ wb) {
    const int i = blockIdx.x * 256 + threadIdx.x;   // 16384
    wb[i] = (__bf16)W[i];
}

// h = fp8(x @ W^T + b) via MFMA 16x16x32 bf16, batched over t (blockIdx.y).
// Frag layouts (m89/m120-verified): A[m=lane&15][k=(lane>>4)*8+j],
// B[n=lane&15][k=(lane>>4)*8+j], C/D row=(lane>>4)*4+reg, col=lane&15.
__global__ __launch_bounds__(256) void gemm_mfma_kernel(const float* __restrict__ xs,
                                                        const __bf16* __restrict__ wb,
                                                        const float* __restrict__ b,
                                                        u8* __restrict__ h8_all) {
    const int lane = threadIdx.x & 63;
    const int wv   = threadIdx.x >> 6;      // 0..3 -> n-slice
    const int r16  = lane & 15;
    const int quad = lane >> 4;
    const int mb   = blockIdx.x;            // rows [16mb, 16mb+16)
    const int t    = blockIdx.y;
    const float* x = xs + (size_t)t * N_NODES * 128;
    u8* h8         = h8_all + (size_t)t * H_STRIDE;

    bfrag Bf[2][4];
#pragma unroll
    for (int nt = 0; nt < 2; ++nt) {
        const int c = wv * 32 + nt * 16 + r16;
#pragma unroll
        for (int ks = 0; ks < 4; ++ks)
            Bf[nt][ks] = *(const bfrag*)(wb + c * 128 + ks * 32 + quad * 8);
    }

    const float* xp = x + (size_t)(mb * 16 + r16) * 128 + quad * 8;
    bfrag Af[4];
#pragma unroll
    for (int ks = 0; ks < 4; ++ks) {
        const float* ap = xp + ks * 32;
#pragma unroll
        for (int j = 0; j < 8; ++j) Af[ks][j] = (__bf16)ap[j];
    }

    f32x4 acc0 = {0.f, 0.f, 0.f, 0.f};
    f32x4 acc1 = {0.f, 0.f, 0.f, 0.f};
#pragma unroll
    for (int ks = 0; ks < 4; ++ks) {
        acc0 = __builtin_amdgcn_mfma_f32_16x16x32_bf16(Af[ks], Bf[0][ks], acc0, 0, 0, 0);
        acc1 = __builtin_amdgcn_mfma_f32_16x16x32_bf16(Af[ks], Bf[1][ks], acc1, 0, 0, 0);
    }

    const int c0 = wv * 32 + r16;
    const float b0 = b[c0], b1 = b[c0 + 16];
#pragma unroll
    for (int r = 0; r < 4; ++r) {
        const size_t row = (size_t)(mb * 16 + quad * 4 + r) * 128;
        h8[row + c0]      = f32_to_fp8(acc0[r] + b0);
        h8[row + c0 + 16] = f32_to_fp8(acc1[r] + b1);
    }
}

// Bucket-partition the edge stream: record (dst&255)<<16 | src into per-bucket
// regions. Per-block LDS counts -> ONE global atomic per (block,bucket)
// reserves a contiguous slice -> each block's ~64 records per bucket land in
// consecutive slots (lines fully dirtied within one block's lifetime -- the
// R4 lesson: csr scatter failed because a line's writes spanned the whole
// kernel; here write-back ~= payload). XCD-pinned: t = (blockIdx&7)>>1.
__global__ __launch_bounds__(256) void part_kernel(const int* __restrict__ edges,
                                                   u32* __restrict__ gcnt,
                                                   u32* __restrict__ recs) {
    __shared__ u32 bh[NBKT], bc[NBKT];
    const int id  = blockIdx.x;              // 512 blocks
    const int xcd = id & 7;
    const int t   = xcd >> 1;
    const int c   = ((xcd & 1) << 6) | (id >> 3);   // chunk 0..127
    const int base = c * CHUNK;
    const int* src = edges + (size_t)t * 2 * E_EDGES;
    const int* dst = src + E_EDGES;
    u32* rt = recs + (size_t)t * NBKT * BCAP;
    const int tid = threadIdx.x;

    if (tid < NBKT) bh[tid] = 0;
    __syncthreads();
    for (int i = tid; i < CHUNK; i += 256)
        atomicAdd(&bh[dst[base + i] >> 8], 1u);
    __syncthreads();
    if (tid < NBKT) bc[tid] = atomicAdd(&gcnt[t * 256 + tid], bh[tid]);
    __syncthreads();
    for (int i = tid; i < CHUNK; i += 256) {
        const int d = dst[base + i];
        const int s = src[base + i];
        const int bkt = d >> 8;
        const u32 idx = atomicAdd(&bc[bkt], 1u);
        if (idx < (u32)BCAP)
            rt[(size_t)bkt * BCAP + idx] = ((u32)(d & 255) << 16) | (u32)s;
    }
}

// Exclusive prefix over the 196 bucket counts per t -> bucket bases.
__global__ __launch_bounds__(256) void bscan_kernel(const u32* __restrict__ gcnt,
                                                    u32* __restrict__ bbase) {
    __shared__ u32 sc[256];
    const int tid = threadIdx.x;
    for (int t = 0; t < T_STEPS; ++t) {
        u32 v = (tid < NBKT) ? min(gcnt[t * 256 + tid], (u32)BCAP) : 0u;
        const u32 mine = v;
        sc[tid] = v;
        __syncthreads();
        for (int d = 1; d < 256; d <<= 1) {
            const u32 u = (tid >= d) ? sc[tid - d] : 0u;
            __syncthreads();
            sc[tid] += u;
            __syncthreads();
        }
        if (tid < NBKT) bbase[t * 256 + tid] = sc[tid] - mine;
        __syncthreads();
    }
}

// One block per (t,bucket): LDS histogram over the bucket's 256 nodes, LDS
// scan, LDS scatter into a dense csr segment, coalesced write-out + row_start.
// All scattered stores hit LDS; global writes are dense (payload-only).
__global__ __launch_bounds__(256) void build_kernel(const u32* __restrict__ recs,
                                                    const u32* __restrict__ gcnt,
                                                    const u32* __restrict__ bbase,
                                                    int* __restrict__ rs_all,
                                                    u16* __restrict__ csr_all) {
    __shared__ u32 ncnt[256];
    __shared__ u32 ncur[256];
    __shared__ u16 cl[BCAP];                 // 20 KB
    const int id  = blockIdx.x;              // 784 blocks = 8 xcd * 98
    const int xcd = id & 7;
    const int t   = xcd >> 1;
    const int b   = ((xcd & 1) ? 98 : 0) + (id >> 3);   // bucket 0..195
    const int tid = threadIdx.x;
    const u32 cnt   = min(gcnt[t * 256 + b], (u32)BCAP);
    const u32 rbase = bbase[t * 256 + b];
    const u32* rp = recs + ((size_t)t * NBKT + b) * BCAP;
    int* rs  = rs_all + (size_t)t * (RS_STRIDE / 4);
    u16* csr = csr_all + (size_t)t * (CSR_STRIDE / 2);

    ncnt[tid] = 0;
    __syncthreads();
    for (u32 i = tid; i < cnt; i += 256)
        atomicAdd(&ncnt[rp[i] >> 16], 1u);
    __syncthreads();
    const u32 mine = ncnt[tid];
    for (int d = 1; d < 256; d <<= 1) {      // inclusive scan
        const u32 v = (tid >= d) ? ncnt[tid - d] : 0u;
        __syncthreads();
        ncnt[tid] += v;
        __syncthreads();
    }
    const u32 off = ncnt[tid] - mine;        // exclusive
    ncur[tid] = off;
    const int n = b * 256 + tid;
    if (n <= N_NODES) rs[n] = (int)(rbase + off);   // rs[50000]=E via b=195
    __syncthreads();
    for (u32 i = tid; i < cnt; i += 256) {
        const u32 r = rp[i];
        const u32 p = atomicAdd(&ncur[r >> 16], 1u);
        cl[p] = (u16)(r & 0xFFFFu);
    }
    __syncthreads();
    for (u32 i = tid; i < cnt; i += 256)
        csr[rbase + i] = cl[i];
}

// One wave per dst node. fp8 rows (128B); half-wave k reads edge 2j+k, lane
// q=lane&31 holds 4 channels/dword. 8 edges/iter = 4 independent load instrs
// in flight. XCD-pinned: each t's h8 (6.4MB) is L2-resident in its XCD
// pair's 8MB (validated R3: fill FETCH halved -> mapping confirmed).
__global__ __launch_bounds__(256) void gather_kernel(const u32* __restrict__ h8_all,
                                                     const int* __restrict__ rs_all,
                                                     const u16* __restrict__ csr_all,
                                                     float* __restrict__ zp_all) {
    const int lane = threadIdx.x & 63;
    const int wv   = __builtin_amdgcn_readfirstlane((int)(threadIdx.x >> 6));
    const int q    = lane & 31;
    const bool h0  = lane < 32;
    const int o    = h0 ? 0 : 1;            // edge offset within pair
    const int id   = blockIdx.x;             // 8192 blocks total
    const int xcd  = id & 7;
    const int t    = xcd >> 1;
    const int kb   = ((xcd & 1) << 10) | (id >> 3);  // 0..2047 within t
    const u32* h8d = h8_all + (size_t)t * (H_STRIDE / 4);
    const int* row_start = rs_all + (size_t)t * (RS_STRIDE / 4);
    const u16* csr = csr_all + (size_t)t * (CSR_STRIDE / 2);
    float* z_pad = zp_all + (size_t)t * (ZP_STRIDE / 4);
    const int gw   = kb * 4 + wv;
    const int nw   = 2048 * 4;              // waves per timestep

    float z0 = 0.f, z1 = 0.f, z2 = 0.f, z3 = 0.f;
    for (int n = gw; n < N_NODES; n += nw) {
        const int rs  = row_start[n];
        const int cnt = row_start[n + 1] - rs;
        // self loop: count once (half 0 only)
        const u32 us = h8d[n * 32 + q];
        const f32x2 slo = __builtin_amdgcn_cvt_pk_f32_fp8(us, 0);
        const f32x2 shi = __builtin_amdgcn_cvt_pk_f32_fp8(us, 1);
        float a0 = h0 ? slo.x : 0.f;
        float a1 = h0 ? slo.y : 0.f;
        float a2 = h0 ? shi.x : 0.f;
        float a3 = h0 ? shi.y : 0.f;

        const u16* lst = csr + rs;
        int i = 0;
        for (; i + 8 <= cnt; i += 8) {       // 4 independent row-pair loads
            const int s0 = lst[i + 0 + o];
            const int s1 = lst[i + 2 + o];
            const int s2 = lst[i + 4 + o];
            const int s3 = lst[i + 6 + o];
            const u32 u0 = h8d[s0 * 32 + q];
            const u32 u1 = h8d[s1 * 32 + q];
            const u32 u2 = h8d[s2 * 32 + q];
            const u32 u3 = h8d[s3 * 32 + q];
            const f32x2 l0 = __builtin_amdgcn_cvt_pk_f32_fp8(u0, 0);
            const f32x2 g0 = __builtin_amdgcn_cvt_pk_f32_fp8(u0, 1);
            const f32x2 l1 = __builtin_amdgcn_cvt_pk_f32_fp8(u1, 0);
            const f32x2 g1 = __builtin_amdgcn_cvt_pk_f32_fp8(u1, 1);
            const f32x2 l2 = __builtin_amdgcn_cvt_pk_f32_fp8(u2, 0);
            const f32x2 g2 = __builtin_amdgcn_cvt_pk_f32_fp8(u2, 1);
            const f32x2 l3 = __builtin_amdgcn_cvt_pk_f32_fp8(u3, 0);
            const f32x2 g3 = __builtin_amdgcn_cvt_pk_f32_fp8(u3, 1);
            a0 += (l0.x + l1.x) + (l2.x + l3.x);
            a1 += (l0.y + l1.y) + (l2.y + l3.y);
            a2 += (g0.x + g1.x) + (g2.x + g3.x);
            a3 += (g0.y + g1.y) + (g2.y + g3.y);
        }
        for (; i + 2 <= cnt; i += 2) {
            const int s = lst[i + o];
            const u32 u = h8d[s * 32 + q];
            const f32x2 lo = __builtin_amdgcn_cvt_pk_f32_fp8(u, 0);
            const f32x2 hi = __builtin_amdgcn_cvt_pk_f32_fp8(u, 1);
            a0 += lo.x; a1 += lo.y; a2 += hi.x; a3 += hi.y;
        }
        if (i < cnt) {                        // odd tail: half 0 only
            const int s = lst[i];
            const u32 u = h8d[s * 32 + q];
            const f32x2 lo = __builtin_amdgcn_cvt_pk_f32_fp8(u, 0);
            const f32x2 hi = __builtin_amdgcn_cvt_pk_f32_fp8(u, 1);
            if (h0) { a0 += lo.x; a1 += lo.y; a2 += hi.x; a3 += hi.y; }
        }
        // combine halves (lane q <-> lane q+32)
        a0 += __shfl_xor(a0, 32);
        a1 += __shfl_xor(a1, 32);
        a2 += __shfl_xor(a2, 32);
        a3 += __shfl_xor(a3, 32);
        const float inv = 1.0f / (float)(cnt + 1);
        z0 += fmaxf(a0 * inv, 0.f);
        z1 += fmaxf(a1 * inv, 0.f);
        z2 += fmaxf(a2 * inv, 0.f);
        z3 += fmaxf(a3 * inv, 0.f);
    }

    // both halves hold identical z -> sum over all 64 lanes counts 2x; scale 0.5
    __shared__ float red[4][64][4];
    red[wv][lane][0] = z0;
    red[wv][lane][1] = z1;
    red[wv][lane][2] = z2;
    red[wv][lane][3] = z3;
    __syncthreads();
    if (threadIdx.x < 128) {
        const int c = threadIdx.x;          // channel
        const int g = c >> 2, m = c & 3;
        float s = 0.f;
#pragma unroll
        for (int w = 0; w < 4; ++w) s += red[w][g][m] + red[w][g + 32][m];
        atomicAdd(&z_pad[c * 32], 0.5f * s);   // 128 slots, 128B apart
    }
}

// All 4 GRU steps + classifier in one block; h lives in LDS the whole time.
__global__ __launch_bounds__(512) void gru_all_kernel(const float* __restrict__ zp_all,
                                                      const float* __restrict__ W_ih,
                                                      const float* __restrict__ W_hh,
                                                      const float* __restrict__ b_ih,
                                                      const float* __restrict__ b_hh,
                                                      const float* __restrict__ W_cls,
                                                      const float* __restrict__ b_cls,
                                                      float* __restrict__ out) {
    __shared__ float zm[128], hs[128], gi[384], gh[384];
    const int tid = threadIdx.x;
    if (tid < 128) hs[tid] = 0.f;
    for (int t = 0; t < T_STEPS; ++t) {
        if (tid < 128)
            zm[tid] = zp_all[(size_t)t * (ZP_STRIDE / 4) + tid * 32] * (1.0f / (float)N_NODES);
        __syncthreads();
        if (tid < 384) {
            float a = b_ih[tid], g = b_hh[tid];
            const float* wi = W_ih + tid * 128;
            const float* wh = W_hh + tid * 128;
#pragma unroll 8
            for (int k = 0; k < 128; ++k) {
                a = fmaf(zm[k], wi[k], a);
                g = fmaf(hs[k], wh[k], g);
            }
            gi[tid] = a;
            gh[tid] = g;
        }
        __syncthreads();
        if (tid < 128) {
            const float r  = 1.f / (1.f + expf(-(gi[tid] + gh[tid])));
            const float zg = 1.f / (1.f + expf(-(gi[128 + tid] + gh[128 + tid])));
            const float ng = tanhf(gi[256 + tid] + r * gh[256 + tid]);
            hs[tid] = (1.f - zg) * ng + zg * hs[tid];
        }
        __syncthreads();
    }
    if (tid < OUT_CH) {
        float a = b_cls[tid];
        const float* wc = W_cls + tid * 128;
#pragma unroll 8
        for (int k = 0; k < 128; ++k) a = fmaf(hs[k], wc[k], a);
        out[tid] = a;
    }
}

extern "C" void kernel_launch(void* const* d_in, const int* in_sizes, int n_in,
                              void* d_out, int out_size, void* d_ws, size_t ws_size,
                              hipStream_t stream) {
    const float* xs    = (const float*)d_in[0];
    const int*   edges = (const int*)d_in[1];
    const float* W_gcn = (const float*)d_in[2];
    const float* b_gcn = (const float*)d_in[3];
    const float* W_ih  = (const float*)d_in[4];
    const float* W_hh  = (const float*)d_in[5];
    const float* b_ih  = (const float*)d_in[6];
    const float* b_hh  = (const float*)d_in[7];
    const float* W_cls = (const float*)d_in[8];
    const float* b_cls = (const float*)d_in[9];
    float* out = (float*)d_out;

    char* ws = (char*)d_ws;
    u8*    h8        = (u8*)(ws + OFF_H);
    int*   row_start = (int*)(ws + OFF_RS);
    float* z_pad     = (float*)(ws + OFF_ZPAD);
    u16*   csr       = (u16*)(ws + OFF_CSR);
    __bf16* wb       = (__bf16*)(ws + OFF_WB);
    u32*   gcnt      = (u32*)(ws + OFF_GCNT);
    u32*   bbase     = (u32*)(ws + OFF_BBASE);
    u32*   recs      = (u32*)(ws + OFF_RECS);

    // zero z accumulators + bucket counters (ws re-poisoned 0xAA per launch)
    hipMemsetAsync(z_pad, 0, 4 * ZP_STRIDE, stream);
    hipMemsetAsync(gcnt, 0, 4096, stream);
    wbf_kernel<<<64, 256, 0, stream>>>(W_gcn, wb);

    // batched over all 4 timesteps; only the GRU is recurrent
    gemm_mfma_kernel<<<dim3(3125, T_STEPS), 256, 0, stream>>>(xs, wb, b_gcn, h8);
    part_kernel<<<NCHUNK * T_STEPS, 256, 0, stream>>>(edges, gcnt, recs);
    bscan_kernel<<<1, 256, 0, stream>>>(gcnt, bbase);
    build_kernel<<<98 * 8, 256, 0, stream>>>(recs, gcnt, bbase, row_start, csr);
    gather_kernel<<<2048 * T_STEPS, 256, 0, stream>>>((const u32*)h8, row_start, csr, z_pad);
    gru_all_kernel<<<1, 512, 0, stream>>>(z_pad, W_ih, W_hh, b_ih, b_hh,
                                          W_cls, b_cls, out);
}